// Round 1
// baseline (418.959 us; speedup 1.0000x reference)
//
#include <hip/hip_runtime.h>

// FlashAttention fwd, causal. B=2, S=2048, H=16, D=64, fp32 in/out.
// Layout [B,S,H,D]: row (b,s,h) is 64 contiguous floats; s-stride = H*D = 1024.

typedef __bf16  bf16x8_t  __attribute__((ext_vector_type(8)));
typedef short   short8_t  __attribute__((ext_vector_type(8)));
typedef float   f32x4     __attribute__((ext_vector_type(4)));

#define MFMA16(a, b, c) __builtin_amdgcn_mfma_f32_16x16x32_bf16((a), (b), (c), 0, 0, 0)

constexpr int   BATCH = 2, SEQ = 2048, NH = 16, DH = 64;
constexpr int   SROW  = NH * DH;          // 1024 floats between consecutive s
constexpr float SCALE = 0.125f;           // 1/sqrt(64)
constexpr float LOG2E = 1.44269504088896f;

// float -> bf16 (RNE), manual so we don't depend on __bf16 arithmetic conversions
__device__ __forceinline__ short f2bf(float f) {
    unsigned u = __builtin_bit_cast(unsigned, f);
    u = (u + 0x7FFFu + ((u >> 16) & 1u)) >> 16;
    return (short)u;
}

__device__ __forceinline__ bf16x8_t load8_bf(const float* __restrict__ p, float scale) {
    const float4* p4 = (const float4*)p;
    float4 a = p4[0];
    float4 b = p4[1];
    short8_t t;
    t[0] = f2bf(a.x * scale); t[1] = f2bf(a.y * scale);
    t[2] = f2bf(a.z * scale); t[3] = f2bf(a.w * scale);
    t[4] = f2bf(b.x * scale); t[5] = f2bf(b.y * scale);
    t[6] = f2bf(b.z * scale); t[7] = f2bf(b.w * scale);
    return __builtin_bit_cast(bf16x8_t, t);
}

__global__ __launch_bounds__(256) void fa_fwd(const float* __restrict__ Q,
                                              const float* __restrict__ K,
                                              const float* __restrict__ V,
                                              float* __restrict__ O) {
    // heavy q-tiles first (causal: work grows with qt)
    const int qt   = (int)gridDim.x - 1 - (int)blockIdx.x;
    const int bh   = blockIdx.y;
    const int b    = bh >> 4;
    const int h    = bh & 15;
    const int wave = threadIdx.x >> 6;
    const int lane = threadIdx.x & 63;
    const int lhi  = lane >> 4;   // quad 0..3
    const int llo  = lane & 15;

    const int q0 = qt * 64 + wave * 16;   // this wave's first q row

    // ---- Q A-fragments (held in regs for whole kernel). A[m=llo][k=lhi*8+j]
    const float* qptr = Q + (size_t)((b * SEQ + q0 + llo) * SROW + h * DH + lhi * 8);
    const bf16x8_t qf0 = load8_bf(qptr,      SCALE);  // d = 0..31 slice
    const bf16x8_t qf1 = load8_bf(qptr + 32, SCALE);  // d = 32..63 slice

    const float* Kbase = K + (size_t)(b * SEQ * SROW + h * DH);
    const float* Vbase = V + (size_t)(b * SEQ * SROW + h * DH);

    // P tile staging (C-layout -> A-layout), per-wave private region.
    // Row stride 72 shorts = 144 B: rotates banks by 4/row -> 2-way (free).
    __shared__ __align__(16) unsigned short Plds[4][16][72];

    float m_i[4], l_i[4];
    f32x4 acc[4];
#pragma unroll
    for (int r = 0; r < 4; ++r) { m_i[r] = -INFINITY; l_i[r] = 0.0f; }
#pragma unroll
    for (int nt = 0; nt < 4; ++nt) acc[nt] = (f32x4){0.f, 0.f, 0.f, 0.f};

    for (int kt = 0; kt <= qt; ++kt) {
        const int kv0 = kt * 64;

        // ---- S = Q K^T for 16 x 64 block, 4 n-tiles
        f32x4 s[4];
#pragma unroll
        for (int nt = 0; nt < 4; ++nt) {
            const float* kptr = Kbase + (size_t)(kv0 + nt * 16 + llo) * SROW + lhi * 8;
            bf16x8_t kf0 = load8_bf(kptr,      1.0f);
            bf16x8_t kf1 = load8_bf(kptr + 32, 1.0f);
            f32x4 z = (f32x4){0.f, 0.f, 0.f, 0.f};
            z = MFMA16(qf0, kf0, z);
            z = MFMA16(qf1, kf1, z);
            s[nt] = z;
        }

        // ---- causal mask (only the diagonal tile needs it)
        if (kt == qt) {
            const int rowb = q0 + lhi * 4;
#pragma unroll
            for (int nt = 0; nt < 4; ++nt) {
                const int col = kv0 + nt * 16 + llo;
#pragma unroll
                for (int r = 0; r < 4; ++r)
                    if (col > rowb + r) s[nt][r] = -INFINITY;
            }
        }

        // ---- online softmax. C-layout: row=(lhi*4+r), col=(nt*16+llo)
        float mt[4];
#pragma unroll
        for (int r = 0; r < 4; ++r) {
            float v = fmaxf(fmaxf(s[0][r], s[1][r]), fmaxf(s[2][r], s[3][r]));
            v = fmaxf(v, __shfl_xor(v, 1));
            v = fmaxf(v, __shfl_xor(v, 2));
            v = fmaxf(v, __shfl_xor(v, 4));
            v = fmaxf(v, __shfl_xor(v, 8));
            mt[r] = v;
        }
        float alpha[4];
#pragma unroll
        for (int r = 0; r < 4; ++r) {
            float mn = fmaxf(m_i[r], mt[r]);
            alpha[r] = exp2f((m_i[r] - mn) * LOG2E);
            m_i[r]   = mn;
        }

        float rs[4] = {0.f, 0.f, 0.f, 0.f};
#pragma unroll
        for (int nt = 0; nt < 4; ++nt) {
#pragma unroll
            for (int r = 0; r < 4; ++r) {
                float p = exp2f((s[nt][r] - m_i[r]) * LOG2E);
                rs[r] += p;
                Plds[wave][lhi * 4 + r][nt * 16 + llo] = (unsigned short)f2bf(p);
            }
        }
#pragma unroll
        for (int r = 0; r < 4; ++r) {
            float v = rs[r];
            v += __shfl_xor(v, 1);
            v += __shfl_xor(v, 2);
            v += __shfl_xor(v, 4);
            v += __shfl_xor(v, 8);
            l_i[r] = l_i[r] * alpha[r] + v;
        }
#pragma unroll
        for (int nt = 0; nt < 4; ++nt)
#pragma unroll
            for (int r = 0; r < 4; ++r) acc[nt][r] *= alpha[r];

        __syncthreads();   // P writes visible before A-layout reads

        // ---- O += P V.  A[m=llo][k=lhi*8+j] from LDS; B[k][n=llo] from global
#pragma unroll
        for (int ks = 0; ks < 2; ++ks) {
            bf16x8_t pf = *(const bf16x8_t*)&Plds[wave][llo][ks * 32 + lhi * 8];
            const float* vptr = Vbase + (size_t)(kv0 + ks * 32 + lhi * 8) * SROW + llo;
#pragma unroll
            for (int nt = 0; nt < 4; ++nt) {
                short8_t t;
#pragma unroll
                for (int j = 0; j < 8; ++j)
                    t[j] = f2bf(vptr[j * SROW + nt * 16]);
                bf16x8_t vf = __builtin_bit_cast(bf16x8_t, t);
                acc[nt] = MFMA16(pf, vf, acc[nt]);
            }
        }

        __syncthreads();   // protect P region from next iteration's writes
    }

    // ---- epilogue: O = acc / l
    float inv[4];
#pragma unroll
    for (int r = 0; r < 4; ++r) inv[r] = 1.0f / l_i[r];

    float* obase = O + (size_t)((b * SEQ + q0) * SROW + h * DH);
#pragma unroll
    for (int nt = 0; nt < 4; ++nt)
#pragma unroll
        for (int r = 0; r < 4; ++r)
            obase[(size_t)(lhi * 4 + r) * SROW + nt * 16 + llo] = acc[nt][r] * inv[r];
}

extern "C" void kernel_launch(void* const* d_in, const int* in_sizes, int n_in,
                              void* d_out, int out_size, void* d_ws, size_t ws_size,
                              hipStream_t stream) {
    const float* q = (const float*)d_in[0];
    const float* k = (const float*)d_in[1];
    const float* v = (const float*)d_in[2];
    float* o = (float*)d_out;
    dim3 grid(SEQ / 64, BATCH * NH);   // 32 x 32 = 1024 blocks
    fa_fwd<<<grid, 256, 0, stream>>>(q, k, v, o);
}

// Round 2
// 166.268 us; speedup vs baseline: 2.5198x; 2.5198x over previous
//
#include <hip/hip_runtime.h>

// FlashAttention fwd, causal. B=2, S=2048, H=16, D=64, fp32 in/out.
// Layout [B,S,H,D]: row (b,s,h) is 64 contiguous floats; s-stride = H*D = 1024 floats.
//
// R2 design: block = 128 thr (2 waves), 64 q rows/block (each wave 32 q rows = 2 m-frags).
// K,V staged cooperatively into LDS as bf16; V transposed in LDS (Vraw->Vt) so PV
// fragments are contiguous ds_read_b128. Register prefetch of next tile hides HBM latency.
// Row-sums (softmax denominator) accumulated via an extra MFMA against a ones fragment.
// Grid: 1024 blocks; tile-order permutation gives constant 66 iters per CU under
// breadth-first dispatch; bh = id&31 keeps each head on one XCD slot (id%8 const).

typedef __bf16  bf16x8_t  __attribute__((ext_vector_type(8)));
typedef short   short8_t  __attribute__((ext_vector_type(8)));
typedef float   f32x4     __attribute__((ext_vector_type(4)));

#define MFMA16(a, b, c) __builtin_amdgcn_mfma_f32_16x16x32_bf16((a), (b), (c), 0, 0, 0)

constexpr int   BATCH = 2, SEQ = 2048, NH = 16, DH = 64;
constexpr int   SROW  = NH * DH;          // 1024 floats between consecutive s
constexpr float SCALE = 0.125f;           // 1/sqrt(64)
constexpr float LOG2E = 1.44269504088896f;

#if __has_builtin(__builtin_amdgcn_cvt_pk_bf16_f32)
__device__ __forceinline__ unsigned pk2(float x, float y) {
    typedef __bf16 bfv2 __attribute__((ext_vector_type(2)));
    bfv2 v = __builtin_amdgcn_cvt_pk_bf16_f32(x, y);
    return __builtin_bit_cast(unsigned, v);
}
#else
__device__ __forceinline__ unsigned f2bfu(float f) {
    unsigned u = __builtin_bit_cast(unsigned, f);
    return (u + 0x7fffu + ((u >> 16) & 1u)) >> 16;
}
__device__ __forceinline__ unsigned pk2(float x, float y) {
    return (f2bfu(x) & 0xffffu) | (f2bfu(y) << 16);
}
#endif

__device__ __forceinline__ unsigned permb(unsigned s0, unsigned s1, unsigned sel) {
    return __builtin_amdgcn_perm(s0, s1, sel);   // idx 0-3 -> s1 bytes, 4-7 -> s0 bytes
}

__global__ __launch_bounds__(128, 2) void fa_fwd(const float* __restrict__ Q,
                                                 const float* __restrict__ K,
                                                 const float* __restrict__ V,
                                                 float* __restrict__ O) {
    const int id = blockIdx.x;
    const int t  = id >> 5;      // tile-order 0..31 (heavy first)
    const int bh = id & 31;      // same bh -> same id%8 -> same XCD slot
    const int b  = bh >> 4, h = bh & 15;
    // Balanced tile permutation: groups {t, t+8, t+16, t+24} sum to 62 (iters 66).
    int T;
    if      (t <  8) T = 31 - t;
    else if (t < 16) T = t - 8;
    else if (t < 24) T = 39 - t;
    else             T = t - 16;

    const int tid  = threadIdx.x;
    const int wave = tid >> 6;
    const int lane = tid & 63;
    const int lhi  = lane >> 4;   // quad 0..3
    const int llo  = lane & 15;
    const int q0w  = T * 64 + wave * 32;   // this wave's first q row

    __shared__ __align__(16) unsigned short Klds[64][72];     // [kv][d]
    __shared__ __align__(16) unsigned short Vraw[64][72];     // [kv][d]
    __shared__ __align__(16) unsigned short Vt  [64][72];     // [d][kv]
    __shared__ __align__(16) unsigned short Plds[2][32][72];  // per-wave, col^8*((row>>2)&3)

    // ---- Q fragments, held in regs; scale folded (exact, pow2) ----
    bf16x8_t qf[2][2];
#pragma unroll
    for (int mt = 0; mt < 2; ++mt)
#pragma unroll
        for (int ks = 0; ks < 2; ++ks) {
            const float* qp = Q + (size_t)((b * SEQ + q0w + mt * 16 + llo) * SROW + h * DH + ks * 32 + lhi * 8);
            float4 a = ((const float4*)qp)[0], c = ((const float4*)qp)[1];
            uint4 u;
            u.x = pk2(a.x * SCALE, a.y * SCALE); u.y = pk2(a.z * SCALE, a.w * SCALE);
            u.z = pk2(c.x * SCALE, c.y * SCALE); u.w = pk2(c.z * SCALE, c.w * SCALE);
            qf[mt][ks] = __builtin_bit_cast(bf16x8_t, u);
        }

    const float* Kbase = K + (size_t)(b * SEQ * SROW + h * DH);
    const float* Vbase = V + (size_t)(b * SEQ * SROW + h * DH);

    // staging roles: 8 passes; pass p: rows sr+8p, 16 lanes cover one row (256B coalesced)
    const int sr  = tid >> 4;     // 0..7
    const int sf4 = tid & 15;     // float4 index in row -> d = 4*sf4
    // transpose roles: d-pair dp (d=2dp,2dp+1), kv-chunks cb, cb+1 (8 kv each)
    const int dp  = tid & 31;
    const int cb  = (tid >> 5) * 2;

    float4 pk4[8], pv4[8];
#pragma unroll
    for (int p = 0; p < 8; ++p) {
        const int r = sr + p * 8;
        pk4[p] = *(const float4*)(Kbase + (size_t)r * SROW + sf4 * 4);
        pv4[p] = *(const float4*)(Vbase + (size_t)r * SROW + sf4 * 4);
    }

    f32x4 acc[2][4], accL[2];
    float mL[2][4];
#pragma unroll
    for (int mt = 0; mt < 2; ++mt) {
        accL[mt] = (f32x4){0.f, 0.f, 0.f, 0.f};
#pragma unroll
        for (int nt = 0; nt < 4; ++nt) acc[mt][nt] = (f32x4){0.f, 0.f, 0.f, 0.f};
#pragma unroll
        for (int r = 0; r < 4; ++r) mL[mt][r] = -INFINITY;
    }

    bf16x8_t onesf;
    {
        short8_t o;
#pragma unroll
        for (int i = 0; i < 8; ++i) o[i] = (short)0x3F80;   // bf16 1.0
        onesf = __builtin_bit_cast(bf16x8_t, o);
    }

    for (int kt = 0; kt <= T; ++kt) {
        const int kv0 = kt * 64;
        __syncthreads();   // protect LDS writes below vs previous iter's reads

        // ---- write prefetched tile to LDS (bf16) ----
#pragma unroll
        for (int p = 0; p < 8; ++p) {
            const int r = sr + p * 8;
            *(uint2*)&Klds[r][sf4 * 4] = make_uint2(pk2(pk4[p].x, pk4[p].y), pk2(pk4[p].z, pk4[p].w));
            *(uint2*)&Vraw[r][sf4 * 4] = make_uint2(pk2(pv4[p].x, pv4[p].y), pk2(pv4[p].z, pv4[p].w));
        }
        __syncthreads();   // staging visible

        // ---- issue next tile's global loads (latency hidden over this iter) ----
        if (kt < T) {
            const float* kb = Kbase + (size_t)(kv0 + 64) * SROW;
            const float* vb = Vbase + (size_t)(kv0 + 64) * SROW;
#pragma unroll
            for (int p = 0; p < 8; ++p) {
                const int r = sr + p * 8;
                pk4[p] = *(const float4*)(kb + (size_t)r * SROW + sf4 * 4);
                pv4[p] = *(const float4*)(vb + (size_t)r * SROW + sf4 * 4);
            }
        }

        // ---- transpose Vraw[kv][d] -> Vt[d][kv] (b32 reads + v_perm + b128 writes) ----
#pragma unroll
        for (int u = 0; u < 2; ++u) {
            const int c = cb + u;
            unsigned rr[8];
#pragma unroll
            for (int j = 0; j < 8; ++j) rr[j] = *(const unsigned*)&Vraw[c * 8 + j][dp * 2];
            uint4 lo, hi;
            lo.x = permb(rr[1], rr[0], 0x05040100u); lo.y = permb(rr[3], rr[2], 0x05040100u);
            lo.z = permb(rr[5], rr[4], 0x05040100u); lo.w = permb(rr[7], rr[6], 0x05040100u);
            hi.x = permb(rr[1], rr[0], 0x07060302u); hi.y = permb(rr[3], rr[2], 0x07060302u);
            hi.z = permb(rr[5], rr[4], 0x07060302u); hi.w = permb(rr[7], rr[6], 0x07060302u);
            *(uint4*)&Vt[dp * 2    ][c * 8] = lo;
            *(uint4*)&Vt[dp * 2 + 1][c * 8] = hi;
        }

        // ---- S = Q K^T (K frags reused across both m-tiles) ----
        f32x4 s[2][4];
#pragma unroll
        for (int nt = 0; nt < 4; ++nt) {
            bf16x8_t kf0 = *(const bf16x8_t*)&Klds[nt * 16 + llo][lhi * 8];
            bf16x8_t kf1 = *(const bf16x8_t*)&Klds[nt * 16 + llo][32 + lhi * 8];
#pragma unroll
            for (int mt = 0; mt < 2; ++mt) {
                f32x4 z = (f32x4){0.f, 0.f, 0.f, 0.f};
                z = MFMA16(qf[mt][0], kf0, z);
                z = MFMA16(qf[mt][1], kf1, z);
                s[mt][nt] = z;
            }
        }

        // ---- causal mask (diagonal tile only) ----
        if (kt == T) {
#pragma unroll
            for (int mt = 0; mt < 2; ++mt) {
                const int rowb = q0w + mt * 16 + lhi * 4;
#pragma unroll
                for (int nt = 0; nt < 4; ++nt) {
                    const int col = kv0 + nt * 16 + llo;
#pragma unroll
                    for (int r = 0; r < 4; ++r)
                        if (col > rowb + r) s[mt][nt][r] = -INFINITY;
                }
            }
        }

        // ---- online softmax (max via shfl; sum via ones-MFMA below) ----
        float alpha[2][4];
#pragma unroll
        for (int mt = 0; mt < 2; ++mt)
#pragma unroll
            for (int r = 0; r < 4; ++r) {
                float v = fmaxf(fmaxf(s[mt][0][r], s[mt][1][r]), fmaxf(s[mt][2][r], s[mt][3][r]));
                v = fmaxf(v, __shfl_xor(v, 1));
                v = fmaxf(v, __shfl_xor(v, 2));
                v = fmaxf(v, __shfl_xor(v, 4));
                v = fmaxf(v, __shfl_xor(v, 8));
                const float nm = fmaxf(mL[mt][r], v * LOG2E);
                alpha[mt][r] = __builtin_amdgcn_exp2f(mL[mt][r] - nm);
                mL[mt][r] = nm;
            }

        // ---- P = exp(S - m) -> LDS (swizzled); rescale accumulators ----
#pragma unroll
        for (int mt = 0; mt < 2; ++mt) {
#pragma unroll
            for (int nt = 0; nt < 4; ++nt) {
                const int colsw = (nt * 16 + llo) ^ (lhi * 8);
#pragma unroll
                for (int r = 0; r < 4; ++r) {
                    const float p = __builtin_amdgcn_exp2f(__builtin_fmaf(s[mt][nt][r], LOG2E, -mL[mt][r]));
                    Plds[wave][mt * 16 + lhi * 4 + r][colsw] = (unsigned short)(pk2(p, p) & 0xffffu);
                }
            }
#pragma unroll
            for (int nt = 0; nt < 4; ++nt)
#pragma unroll
                for (int r = 0; r < 4; ++r) acc[mt][nt][r] *= alpha[mt][r];
#pragma unroll
            for (int r = 0; r < 4; ++r) accL[mt][r] *= alpha[mt][r];
        }
        __syncthreads();   // P + Vt visible

        // ---- O += P V ; denominator via P*ones ----
#pragma unroll
        for (int ks = 0; ks < 2; ++ks) {
            bf16x8_t pf[2];
#pragma unroll
            for (int mt = 0; mt < 2; ++mt)
                pf[mt] = *(const bf16x8_t*)&Plds[wave][mt * 16 + llo][ks * 32 + 8 * (lhi ^ (llo >> 2))];
#pragma unroll
            for (int nt = 0; nt < 4; ++nt) {
                bf16x8_t vf = *(const bf16x8_t*)&Vt[nt * 16 + llo][ks * 32 + lhi * 8];
#pragma unroll
                for (int mt = 0; mt < 2; ++mt) acc[mt][nt] = MFMA16(pf[mt], vf, acc[mt][nt]);
            }
#pragma unroll
            for (int mt = 0; mt < 2; ++mt) accL[mt] = MFMA16(pf[mt], onesf, accL[mt]);
        }
    }

    // ---- epilogue: accL holds row-sums in exactly the C-layout rows we need ----
#pragma unroll
    for (int mt = 0; mt < 2; ++mt)
#pragma unroll
        for (int r = 0; r < 4; ++r) {
            const float inv = 1.0f / accL[mt][r];
            float* ob = O + (size_t)((b * SEQ + q0w + mt * 16 + lhi * 4 + r) * SROW + h * DH);
#pragma unroll
            for (int nt = 0; nt < 4; ++nt) ob[nt * 16 + llo] = acc[mt][nt][r] * inv;
        }
}

extern "C" void kernel_launch(void* const* d_in, const int* in_sizes, int n_in,
                              void* d_out, int out_size, void* d_ws, size_t ws_size,
                              hipStream_t stream) {
    const float* q = (const float*)d_in[0];
    const float* k = (const float*)d_in[1];
    const float* v = (const float*)d_in[2];
    float* o = (float*)d_out;
    fa_fwd<<<dim3(1024), dim3(128), 0, stream>>>(q, k, v, o);
}

// Round 4
// 143.542 us; speedup vs baseline: 2.9187x; 1.1583x over previous
//
#include <hip/hip_runtime.h>

// FlashAttention fwd, causal. B=2, S=2048, H=16, D=64, fp32 in/out.
// Layout [B,S,H,D]: row (b,s,h) is 64 contiguous floats; s-stride = H*D = 1024 floats.
//
// R3b: compute S^T = K·Q^T (swap MFMA operands) so the P^T C-fragments are
// directly the A-fragments of v_mfma_f32_16x16x16_bf16 (A[m=llo][k=lhi*4+j]).
// P never touches LDS; V is read in natural [kv][d] layout via ds_read_u16
// (2-way bank aliasing = free). 2 barriers/iter, K/V staged by all 4 waves.
// Grid 512 = 16 q-tiles(128 rows) x 32 bh; blocks id and id+256 share a CU
// and have durations (2T+2) summing to 34 -> balanced; heavy tiles first.
// (R3 compile fix: _1k MFMA builtin guarded by __HIP_DEVICE_COMPILE__ —
// __has_builtin is false in the host pass and the old-name fallback doesn't exist.)

typedef __bf16  bf16x8_t  __attribute__((ext_vector_type(8)));
typedef short   short4_t  __attribute__((ext_vector_type(4)));
typedef float   f32x4     __attribute__((ext_vector_type(4)));

#define MFMA_K32(a, b, c) __builtin_amdgcn_mfma_f32_16x16x32_bf16((a), (b), (c), 0, 0, 0)

__device__ __forceinline__ f32x4 mfma_k16(short4_t a, short4_t b, f32x4 c) {
#if defined(__HIP_DEVICE_COMPILE__)
    return __builtin_amdgcn_mfma_f32_16x16x16bf16_1k(a, b, c, 0, 0, 0);
#else
    return c;   // host pass never executes device code; just needs to parse
#endif
}

constexpr int   BATCH = 2, SEQ = 2048, NH = 16, DH = 64;
constexpr int   SROW  = NH * DH;
constexpr float SCALE = 0.125f;
constexpr float LOG2E = 1.44269504088896f;

__device__ __forceinline__ unsigned f2bfu(float f) {
    unsigned u = __builtin_bit_cast(unsigned, f);
    return (u + 0x7fffu + ((u >> 16) & 1u)) >> 16;
}
__device__ __forceinline__ unsigned pk2(float x, float y) {
#if defined(__HIP_DEVICE_COMPILE__) && __has_builtin(__builtin_amdgcn_cvt_pk_bf16_f32)
    typedef __bf16 bfv2 __attribute__((ext_vector_type(2)));
    bfv2 v = __builtin_amdgcn_cvt_pk_bf16_f32(x, y);
    return __builtin_bit_cast(unsigned, v);
#else
    return (f2bfu(x) & 0xffffu) | (f2bfu(y) << 16);
#endif
}

__global__ __launch_bounds__(256, 2) void fa_fwd(const float* __restrict__ Q,
                                                 const float* __restrict__ K,
                                                 const float* __restrict__ V,
                                                 float* __restrict__ O) {
    const int id = blockIdx.x;
    const int bh = id & 31;                 // id%8 fixed per head-group -> XCD locality
    const int g  = id >> 5;                 // 0..15
    const int b  = bh >> 4, h = bh & 15;
    const int T  = (g < 8) ? (15 - g) : (g - 8);   // 128-row q tile; heavy first
    const int nkt = 2 * T + 2;              // kv tiles of 64

    const int tid  = threadIdx.x;
    const int wave = tid >> 6;
    const int lane = tid & 63;
    const int lhi  = lane >> 4;
    const int llo  = lane & 15;
    const int q0   = T * 128 + wave * 32;   // this wave's first q row

    __shared__ __align__(16) unsigned short Kl[64][72];   // [kv][d]
    __shared__ __align__(16) unsigned short Vl[64][72];   // [kv][d]

    // ---- Q fragments (scale folded; same layout serves as MFMA B operand) ----
    bf16x8_t qf[2][2];
#pragma unroll
    for (int mt = 0; mt < 2; ++mt)
#pragma unroll
        for (int ks = 0; ks < 2; ++ks) {
            const float* qp = Q + (size_t)((b * SEQ + q0 + mt * 16 + llo) * SROW + h * DH + ks * 32 + lhi * 8);
            float4 a = ((const float4*)qp)[0], c = ((const float4*)qp)[1];
            uint4 u;
            u.x = pk2(a.x * SCALE, a.y * SCALE); u.y = pk2(a.z * SCALE, a.w * SCALE);
            u.z = pk2(c.x * SCALE, c.y * SCALE); u.w = pk2(c.z * SCALE, c.w * SCALE);
            qf[mt][ks] = __builtin_bit_cast(bf16x8_t, u);
        }

    const float* Kb = K + (size_t)(b * SEQ) * SROW + h * DH;
    const float* Vb = V + (size_t)(b * SEQ) * SROW + h * DH;

    // staging roles: 256 thr cover a 64x64 tile in 4 passes of 16 rows
    const int sr  = tid >> 4;    // 0..15
    const int sf4 = tid & 15;    // float4 index -> d = 4*sf4

    float4 pk[4], pv[4];
#pragma unroll
    for (int p = 0; p < 4; ++p) {
        const int r = sr + p * 16;
        pk[p] = *(const float4*)(Kb + (size_t)r * SROW + sf4 * 4);
        pv[p] = *(const float4*)(Vb + (size_t)r * SROW + sf4 * 4);
    }

    f32x4 acc[2][4], accL[2];
    float mL[2];
#pragma unroll
    for (int mt = 0; mt < 2; ++mt) {
        mL[mt] = -INFINITY;
        accL[mt] = (f32x4){0.f, 0.f, 0.f, 0.f};
#pragma unroll
        for (int dt = 0; dt < 4; ++dt) acc[mt][dt] = (f32x4){0.f, 0.f, 0.f, 0.f};
    }

    short4_t ones;
#pragma unroll
    for (int j = 0; j < 4; ++j) ones[j] = (short)0x3F80;   // bf16 1.0

    for (int kt = 0; kt < nkt; ++kt) {
        const int kv0 = kt * 64;
        __syncthreads();   // protect staging writes vs previous iteration's reads

        // ---- write prefetched K/V tile to LDS as bf16 ----
#pragma unroll
        for (int p = 0; p < 4; ++p) {
            const int r = sr + p * 16;
            *(uint2*)&Kl[r][sf4 * 4] = make_uint2(pk2(pk[p].x, pk[p].y), pk2(pk[p].z, pk[p].w));
            *(uint2*)&Vl[r][sf4 * 4] = make_uint2(pk2(pv[p].x, pv[p].y), pk2(pv[p].z, pv[p].w));
        }
        __syncthreads();   // staging visible

        // ---- issue next tile's global loads (hidden across this iteration) ----
        if (kt + 1 < nkt) {
            const float* kb = Kb + (size_t)(kv0 + 64) * SROW;
            const float* vb = Vb + (size_t)(kv0 + 64) * SROW;
#pragma unroll
            for (int p = 0; p < 4; ++p) {
                const int r = sr + p * 16;
                pk[p] = *(const float4*)(kb + (size_t)r * SROW + sf4 * 4);
                pv[p] = *(const float4*)(vb + (size_t)r * SROW + sf4 * 4);
            }
        }

        // waves whose rows are all < kv0 are fully masked: staging-only
        if (kv0 > q0 + 31) continue;

        // ---- S^T = K·Q^T : C holds S^T[kv=lhi*4+r][m=llo] ----
        f32x4 s[2][4];
#pragma unroll
        for (int nt = 0; nt < 4; ++nt) {
            bf16x8_t kf0 = *(const bf16x8_t*)&Kl[nt * 16 + llo][lhi * 8];
            bf16x8_t kf1 = *(const bf16x8_t*)&Kl[nt * 16 + llo][32 + lhi * 8];
#pragma unroll
            for (int mt = 0; mt < 2; ++mt) {
                f32x4 z = (f32x4){0.f, 0.f, 0.f, 0.f};
                z = MFMA_K32(kf0, qf[mt][0], z);
                z = MFMA_K32(kf1, qf[mt][1], z);
                s[mt][nt] = z;
            }
        }

        // ---- causal mask: element (kv, m) masked if kv > m ----
#pragma unroll
        for (int mt = 0; mt < 2; ++mt) {
            const int m_g = q0 + mt * 16 + llo;
            if (kv0 + 63 > q0 + mt * 16) {
#pragma unroll
                for (int nt = 0; nt < 4; ++nt)
#pragma unroll
                    for (int r = 0; r < 4; ++r)
                        if (kv0 + nt * 16 + lhi * 4 + r > m_g) s[mt][nt][r] = -INFINITY;
            }
        }

        // ---- online softmax in transposed (per-column) domain ----
        short4_t pf[2][4];
#pragma unroll
        for (int mt = 0; mt < 2; ++mt) {
            float cm = s[mt][0][0];
#pragma unroll
            for (int nt = 0; nt < 4; ++nt)
#pragma unroll
                for (int r = 0; r < 4; ++r) cm = fmaxf(cm, s[mt][nt][r]);
            cm = fmaxf(cm, __shfl_xor(cm, 16));
            cm = fmaxf(cm, __shfl_xor(cm, 32));
            const float nm = fmaxf(mL[mt], cm * LOG2E);
            const float alpha = __builtin_amdgcn_exp2f(mL[mt] - nm);
            mL[mt] = nm;
#pragma unroll
            for (int nt = 0; nt < 4; ++nt) {
                float p0 = __builtin_amdgcn_exp2f(__builtin_fmaf(s[mt][nt][0], LOG2E, -nm));
                float p1 = __builtin_amdgcn_exp2f(__builtin_fmaf(s[mt][nt][1], LOG2E, -nm));
                float p2 = __builtin_amdgcn_exp2f(__builtin_fmaf(s[mt][nt][2], LOG2E, -nm));
                float p3 = __builtin_amdgcn_exp2f(__builtin_fmaf(s[mt][nt][3], LOG2E, -nm));
                uint2 u = make_uint2(pk2(p0, p1), pk2(p2, p3));
                pf[mt][nt] = __builtin_bit_cast(short4_t, u);
            }
            // alpha is per column m=llo; acc rows are lhi*4+r -> transpose via shfl
#pragma unroll
            for (int r = 0; r < 4; ++r) {
                const float aT = __shfl(alpha, lhi * 4 + r);
#pragma unroll
                for (int dt = 0; dt < 4; ++dt) acc[mt][dt][r] *= aT;
                accL[mt][r] *= aT;
            }
        }

        // ---- O += P·V (K=16 MFMAs; P frags already in regs) ----
#pragma unroll
        for (int ks = 0; ks < 4; ++ks) {
#pragma unroll
            for (int dt = 0; dt < 4; ++dt) {
                short4_t vf;
#pragma unroll
                for (int j = 0; j < 4; ++j)
                    vf[j] = (short)Vl[ks * 16 + lhi * 4 + j][dt * 16 + llo];
#pragma unroll
                for (int mt = 0; mt < 2; ++mt)
                    acc[mt][dt] = mfma_k16(pf[mt][ks], vf, acc[mt][dt]);
            }
#pragma unroll
            for (int mt = 0; mt < 2; ++mt)
                accL[mt] = mfma_k16(pf[mt][ks], ones, accL[mt]);
        }
    }

    // ---- epilogue: acc rows = lhi*4+r, cols = dt*16+llo; accL rows match ----
#pragma unroll
    for (int mt = 0; mt < 2; ++mt)
#pragma unroll
        for (int r = 0; r < 4; ++r) {
            const float inv = 1.0f / accL[mt][r];
            float* ob = O + (size_t)((b * SEQ + q0 + mt * 16 + lhi * 4 + r) * SROW + h * DH);
#pragma unroll
            for (int dt = 0; dt < 4; ++dt) ob[dt * 16 + llo] = acc[mt][dt][r] * inv;
        }
}

extern "C" void kernel_launch(void* const* d_in, const int* in_sizes, int n_in,
                              void* d_out, int out_size, void* d_ws, size_t ws_size,
                              hipStream_t stream) {
    const float* q = (const float*)d_in[0];
    const float* k = (const float*)d_in[1];
    const float* v = (const float*)d_in[2];
    float* o = (float*)d_out;
    fa_fwd<<<dim3(512), dim3(256), 0, stream>>>(q, k, v, o);
}